// Round 6
// baseline (128.024 us; speedup 1.0000x reference)
//
#include <hip/hip_runtime.h>
#include <math.h>
#include <type_traits>

#define T_STEPS 2048
#define NU 512
#define NCH 8192            // B*U independent chains
#define PF 6                // iterations (of 4 steps) prefetched ahead

typedef int i4 __attribute__((ext_vector_type(4)));
template<int N> using ic = std::integral_constant<int, N>;

// Design notes:
//  * NO LDS, NO lgkmcnt: inputs go HBM -> register ring via inline-asm
//    buffer_load_dword (wave-coalesced 256B/row). Suspected gfx950 LDS-DMA
//    lgkm accounting made rounds 4/5 serialize on one memory latency per iter.
//  * vmcnt waits use the sound rule: wait N <= (#loads issued after target
//    load). Loads retire in order; stores sharing vmcnt only make the wait
//    stricter, never unsound. Steady state: ring slot consumed was loaded
//    PF iters ago; loads-after = (PF-1)*8 = 40 -> s_waitcnt vmcnt(40).
//    Outstanding loads <= 48 (< 64 hw cap).
//  * NO sin/cos in the loop: incremental rotation. phi_{t+1} = phi_t + a + eps,
//    a = om*dt const (Ca=cos a, Sa=sin a), eps = -0.05*xi*s small.
//    (s,c) <- rot(a) then first-order rot(eps); norm fixed once per iter by
//    n = (3 - (s^2+c^2))/2. Phase error ~eps^3/2 per step -> ~1e-2 rad total.
__global__ __launch_bounds__(64)
void reshopf_kernel(const float* __restrict__ Xr, const float* __restrict__ Xi,
                    const float* __restrict__ r0, const float* __restrict__ phi0,
                    const float* __restrict__ omegas,
                    float* __restrict__ zr, float* __restrict__ r_f,
                    float* __restrict__ phi_f)
{
    const int lane = threadIdx.x;
    const int g    = blockIdx.x * 64 + lane;
    const int u    = g & (NU - 1);

    const float INV2PI = 0.15915494309189533577f;

    // per-chain constants
    const float wo    = omegas[u];
    const float sig   = 1.0f / (1.0f + __expf(-wo));
    const float a_rev = (sig * 19.5f + 0.5f) * 0.01f;     // om*dt, revolutions
    const float Ca    = __builtin_amdgcn_cosf(a_rev);     // cos(om*dt)
    const float Sa    = __builtin_amdgcn_sinf(a_rev);     // sin(om*dt)

    float r        = r0[g];
    const float p0 = phi0[g];
    float s = __builtin_amdgcn_sinf(p0 * INV2PI);
    float c = __builtin_amdgcn_cosf(p0 * INV2PI);
    float acc = 0.0f;                                     // sum of eps (radians)

    // buffer SRDs (stride 0, raw, bounds check off)
    auto mksrd = [](const void* p) -> i4 {
        i4 v;
        v.x = (int)(unsigned)(uintptr_t)p;
        v.y = (int)((unsigned)((uintptr_t)p >> 32) & 0xFFFFu);
        v.z = (int)0xFFFFFFFFu;
        v.w = 0x00020000;
        return v;
    };
    const i4 srdR = mksrd(Xr), srdI = mksrd(Xi), srdZ = mksrd(zr);
    const unsigned voff = (unsigned)g * 4u;               // lane byte offset in a row

    float rgR[PF][4], rgI[PF][4];                          // register ring (static idx only)

    auto load1 = [&](float& dst, const i4& srd, unsigned soff) {
        asm volatile("buffer_load_dword %0, %1, %2, %3 offen"
                     : "=v"(dst) : "v"(voff), "s"(srd), "s"(soff));
    };
    auto loadgrp = [&](auto Pc, int i) {                   // stage iter i's 4 rows into slot P
        constexpr int P = decltype(Pc)::value;
        const unsigned b = (unsigned)i * 131072u;          // i*4 rows * 32768 B/row
        load1(rgR[P][0], srdR, b);
        load1(rgI[P][0], srdI, b);
        load1(rgR[P][1], srdR, b + 32768u);
        load1(rgI[P][1], srdI, b + 32768u);
        load1(rgR[P][2], srdR, b + 65536u);
        load1(rgI[P][2], srdI, b + 65536u);
        load1(rgR[P][3], srdR, b + 98304u);
        load1(rgI[P][3], srdI, b + 98304u);
    };
    auto store1 = [&](float zv, unsigned soff) {
        asm volatile("buffer_store_dword %0, %1, %2, %3 offen"
                     :: "v"(zv), "v"(voff), "s"(srdZ), "s"(soff) : "memory");
    };

    auto step = [&](float xr, float xi, unsigned soff) {
        const float kxi = xi * -0.05f;                     // off-chain
        const float kxr = xr * 0.05f;                      // off-chain
        const float eps = kxi * s;                         // -5*xi*sin(phi)*dt, radians
        const float t1  = s * Ca;
        const float sA  = fmaf(c, Sa, t1);                 // sin(phi+a)
        const float t2  = c * Ca;
        const float cA  = fmaf(-s, Sa, t2);                // cos(phi+a)
        const float rr  = r * r;
        const float g1  = fmaf(-rr, r, r);                 // (1-r^2)*r
        const float tr  = fmaf(kxr, c, r);                 // uses OLD cos(phi)
        r = fmaf(0.01f, g1, tr);
        s = fmaf(eps, cA, sA);                             // first-order rot(eps)
        c = fmaf(-eps, sA, cA);
        acc += eps;
        store1(r * c, soff);                               // Re(z) = r_new*cos(phi_new)
    };

    auto iter = [&](auto Pc, auto NWc, auto RFc, int i) {
        asm volatile("s_waitcnt vmcnt(%0)" :: "n"(decltype(NWc)::value) : "memory");
        __builtin_amdgcn_sched_barrier(0);
        constexpr int P = decltype(Pc)::value;
        const unsigned sb = (unsigned)i * 131072u;
        step(rgR[P][0], rgI[P][0], sb);
        step(rgR[P][1], rgI[P][1], sb + 32768u);
        step(rgR[P][2], rgI[P][2], sb + 65536u);
        step(rgR[P][3], rgI[P][3], sb + 98304u);
        // norm correction once per 4 steps (drift (1+eps^2)/step)
        const float m = fmaf(s, s, c * c);
        const float n = fmaf(-0.5f, m, 1.5f);
        s *= n; c *= n;
        if constexpr (decltype(RFc)::value) loadgrp(Pc, i + PF);  // refill AFTER consume
    };

    // prologue: 6 slots = 48 loads in flight
    loadgrp(ic<0>{}, 0); loadgrp(ic<1>{}, 1); loadgrp(ic<2>{}, 2);
    loadgrp(ic<3>{}, 3); loadgrp(ic<4>{}, 4); loadgrp(ic<5>{}, 5);

    // main: iters 0..503 (84 blocks of 6), uniform wait vmcnt(40)
    for (int blk = 0; blk < 84; ++blk) {
        const int ib = blk * PF;
        iter(ic<0>{}, ic<40>{}, ic<1>{}, ib + 0);
        iter(ic<1>{}, ic<40>{}, ic<1>{}, ib + 1);
        iter(ic<2>{}, ic<40>{}, ic<1>{}, ib + 2);
        iter(ic<3>{}, ic<40>{}, ic<1>{}, ib + 3);
        iter(ic<4>{}, ic<40>{}, ic<1>{}, ib + 4);
        iter(ic<5>{}, ic<40>{}, ic<1>{}, ib + 5);
    }
    // peeled tail: iters 504..511; last refills target 510/511; waits ramp down
    iter(ic<0>{}, ic<40>{}, ic<1>{}, 504);
    iter(ic<1>{}, ic<40>{}, ic<1>{}, 505);
    iter(ic<2>{}, ic<40>{}, ic<0>{}, 506);
    iter(ic<3>{}, ic<32>{}, ic<0>{}, 507);
    iter(ic<4>{}, ic<24>{}, ic<0>{}, 508);
    iter(ic<5>{}, ic<16>{}, ic<0>{}, 509);
    iter(ic<0>{}, ic<8>{},  ic<0>{}, 510);
    iter(ic<1>{}, ic<0>{},  ic<0>{}, 511);

    r_f[g] = r;
    // phi_f = p0 + 2048*a + sum(eps), widened to f64 at the end
    phi_f[g] = (float)((double)p0
                       + (double)a_rev * 2048.0 * 6.283185307179586476925287
                       + (double)acc);
}

extern "C" void kernel_launch(void* const* d_in, const int* in_sizes, int n_in,
                              void* d_out, int out_size, void* d_ws, size_t ws_size,
                              hipStream_t stream) {
    const float* Xr   = (const float*)d_in[0];
    const float* Xi   = (const float*)d_in[1];
    const float* r0   = (const float*)d_in[2];
    const float* phi0 = (const float*)d_in[3];
    const float* om   = (const float*)d_in[4];

    float* out   = (float*)d_out;
    float* zrp   = out;                               // Re(z): T*NCH floats
    float* r_f   = out + (size_t)T_STEPS * NCH;       // NCH floats
    float* phi_f = r_f + NCH;                         // NCH floats

    reshopf_kernel<<<NCH / 64, 64, 0, stream>>>(Xr, Xi, r0, phi0, om, zrp, r_f, phi_f);
}

// Round 7
// 108.159 us; speedup vs baseline: 1.1837x; 1.1837x over previous
//
#include <hip/hip_runtime.h>
#include <math.h>
#include <type_traits>

#define T_STEPS 2048
#define NU 512
#define NCH 8192            // B*U independent chains
#define PF 7                // iterations (of 4 steps) prefetched ahead

typedef int i4 __attribute__((ext_vector_type(4)));
template<int N> using ic = std::integral_constant<int, N>;

// Round-7 theses:
//  * __launch_bounds__(64, 1): min 1 wave/EU -> VGPR budget 512. Round 6's
//    default occupancy heuristic capped VGPR at 44 and SPILLED the 48-float
//    register ring to scratch (scratch vmem ops serialized every iteration).
//  * ring depth PF=7: 56 loads in flight, + 4 stores <= 60 < 63 vmcnt cap.
//  * waits: sound rule N <= (#vmem ops issued after target op), stores count.
//    steady state: ops-after = 6 iters * 12 = 72 >= 63 -> vmcnt(63) suffices
//    (6-bit outstanding cap guarantees the oldest 17 retired).
//  * NO LDS / NO lgkmcnt anywhere (gfx950 LDS-DMA counts in lgkm -> rounds
//    4/5 serialized). NO sin/cos in loop (incremental rotation, norm fix
//    once per 4 steps; error << threshold, absmax 8.0 vs 38 in round 6).
__global__ __launch_bounds__(64, 1)
void reshopf_kernel(const float* __restrict__ Xr, const float* __restrict__ Xi,
                    const float* __restrict__ r0, const float* __restrict__ phi0,
                    const float* __restrict__ omegas,
                    float* __restrict__ zr, float* __restrict__ r_f,
                    float* __restrict__ phi_f)
{
    const int lane = threadIdx.x;
    const int g    = blockIdx.x * 64 + lane;
    const int u    = g & (NU - 1);

    const float INV2PI = 0.15915494309189533577f;

    // per-chain constants
    const float wo    = omegas[u];
    const float sig   = 1.0f / (1.0f + __expf(-wo));
    const float a_rev = (sig * 19.5f + 0.5f) * 0.01f;     // om*dt, revolutions
    const float Ca    = __builtin_amdgcn_cosf(a_rev);     // cos(om*dt)
    const float Sa    = __builtin_amdgcn_sinf(a_rev);     // sin(om*dt)

    float r        = r0[g];
    const float p0 = phi0[g];
    float s = __builtin_amdgcn_sinf(p0 * INV2PI);
    float c = __builtin_amdgcn_cosf(p0 * INV2PI);
    float acc = 0.0f;                                     // sum of eps (radians)

    // buffer SRDs (stride 0, raw, bounds check disabled)
    auto mksrd = [](const void* p) -> i4 {
        i4 v;
        v.x = (int)(unsigned)(uintptr_t)p;
        v.y = (int)((unsigned)((uintptr_t)p >> 32) & 0xFFFFu);
        v.z = (int)0xFFFFFFFFu;
        v.w = 0x00020000;
        return v;
    };
    const i4 srdR = mksrd(Xr), srdI = mksrd(Xi), srdZ = mksrd(zr);
    const unsigned voff = (unsigned)g * 4u;               // lane byte offset in a row

    float rgR[PF][4], rgI[PF][4];                          // register ring (static idx only)

    auto load1 = [&](float& dst, const i4& srd, unsigned soff) {
        asm volatile("buffer_load_dword %0, %1, %2, %3 offen"
                     : "=v"(dst) : "v"(voff), "s"(srd), "s"(soff));
    };
    auto loadgrp = [&](auto Pc, int i) {                   // stage iter i's 4 rows into slot P
        constexpr int P = decltype(Pc)::value;
        const unsigned b = (unsigned)i * 131072u;          // i*4 rows * 32768 B/row
        load1(rgR[P][0], srdR, b);
        load1(rgI[P][0], srdI, b);
        load1(rgR[P][1], srdR, b + 32768u);
        load1(rgI[P][1], srdI, b + 32768u);
        load1(rgR[P][2], srdR, b + 65536u);
        load1(rgI[P][2], srdI, b + 65536u);
        load1(rgR[P][3], srdR, b + 98304u);
        load1(rgI[P][3], srdI, b + 98304u);
    };
    auto store1 = [&](float zv, unsigned soff) {
        asm volatile("buffer_store_dword %0, %1, %2, %3 offen"
                     :: "v"(zv), "v"(voff), "s"(srdZ), "s"(soff) : "memory");
    };

    auto step = [&](float xr, float xi, unsigned soff) {
        const float kxi = xi * -0.05f;                     // off-chain
        const float kxr = xr * 0.05f;                      // off-chain
        const float eps = kxi * s;                         // -5*xi*sin(phi)*dt, radians
        const float t1  = s * Ca;
        const float sA  = fmaf(c, Sa, t1);                 // sin(phi+a)
        const float t2  = c * Ca;
        const float cA  = fmaf(-s, Sa, t2);                // cos(phi+a)
        const float rr  = r * r;
        const float g1  = fmaf(-rr, r, r);                 // (1-r^2)*r
        const float tr  = fmaf(kxr, c, r);                 // uses OLD cos(phi)
        r = fmaf(0.01f, g1, tr);
        s = fmaf(eps, cA, sA);                             // first-order rot(eps)
        c = fmaf(-eps, sA, cA);
        acc += eps;
        store1(r * c, soff);                               // Re(z) = r_new*cos(phi_new)
    };

    auto iter = [&](auto Pc, auto NWc, auto RFc, int i) {
        asm volatile("s_waitcnt vmcnt(%0)" :: "n"(decltype(NWc)::value) : "memory");
        __builtin_amdgcn_sched_barrier(0);                 // ring reads stay after wait
        constexpr int P = decltype(Pc)::value;
        const unsigned sb = (unsigned)i * 131072u;
        step(rgR[P][0], rgI[P][0], sb);
        step(rgR[P][1], rgI[P][1], sb + 32768u);
        step(rgR[P][2], rgI[P][2], sb + 65536u);
        step(rgR[P][3], rgI[P][3], sb + 98304u);
        // norm correction once per 4 steps (drift ~(1+eps^2) per step)
        const float m = fmaf(s, s, c * c);
        const float n = fmaf(-0.5f, m, 1.5f);
        s *= n; c *= n;
        if constexpr (decltype(RFc)::value) loadgrp(Pc, i + PF);  // refill AFTER consume
    };

    // prologue: 7 slots = 56 loads in flight
    loadgrp(ic<0>{}, 0); loadgrp(ic<1>{}, 1); loadgrp(ic<2>{}, 2);
    loadgrp(ic<3>{}, 3); loadgrp(ic<4>{}, 4); loadgrp(ic<5>{}, 5);
    loadgrp(ic<6>{}, 6);

    // first block: waits ramp 48,52,56,60 then 63 (sound: N <= ops-after-target)
    iter(ic<0>{}, ic<48>{}, ic<1>{}, 0);
    iter(ic<1>{}, ic<52>{}, ic<1>{}, 1);
    iter(ic<2>{}, ic<56>{}, ic<1>{}, 2);
    iter(ic<3>{}, ic<60>{}, ic<1>{}, 3);
    iter(ic<4>{}, ic<63>{}, ic<1>{}, 4);
    iter(ic<5>{}, ic<63>{}, ic<1>{}, 5);
    iter(ic<6>{}, ic<63>{}, ic<1>{}, 6);

    // steady state: iters 7..503 (71 blocks of 7), uniform vmcnt(63)
    for (int blk = 1; blk < 72; ++blk) {
        const int ib = blk * PF;
        iter(ic<0>{}, ic<63>{}, ic<1>{}, ib + 0);
        iter(ic<1>{}, ic<63>{}, ic<1>{}, ib + 1);
        iter(ic<2>{}, ic<63>{}, ic<1>{}, ib + 2);
        iter(ic<3>{}, ic<63>{}, ic<1>{}, ib + 3);
        iter(ic<4>{}, ic<63>{}, ic<1>{}, ib + 4);
        iter(ic<5>{}, ic<63>{}, ic<1>{}, ib + 5);
        iter(ic<6>{}, ic<63>{}, ic<1>{}, ib + 6);
    }
    // iter 504: last refill (grp 511 -> slot 0)
    iter(ic<0>{}, ic<63>{}, ic<1>{}, 504);

    // tail 505..511: no refills; waits ramp down (derived: 63,63,56,48,40,32,24)
    iter(ic<1>{}, ic<63>{}, ic<0>{}, 505);
    iter(ic<2>{}, ic<63>{}, ic<0>{}, 506);
    iter(ic<3>{}, ic<56>{}, ic<0>{}, 507);
    iter(ic<4>{}, ic<48>{}, ic<0>{}, 508);
    iter(ic<5>{}, ic<40>{}, ic<0>{}, 509);
    iter(ic<6>{}, ic<32>{}, ic<0>{}, 510);
    iter(ic<0>{}, ic<24>{}, ic<0>{}, 511);

    r_f[g] = r;
    // phi_f = p0 + 2048*a + sum(eps), widened to f64 at the end
    phi_f[g] = (float)((double)p0
                       + (double)a_rev * 2048.0 * 6.283185307179586476925287
                       + (double)acc);
}

extern "C" void kernel_launch(void* const* d_in, const int* in_sizes, int n_in,
                              void* d_out, int out_size, void* d_ws, size_t ws_size,
                              hipStream_t stream) {
    const float* Xr   = (const float*)d_in[0];
    const float* Xi   = (const float*)d_in[1];
    const float* r0   = (const float*)d_in[2];
    const float* phi0 = (const float*)d_in[3];
    const float* om   = (const float*)d_in[4];

    float* out   = (float*)d_out;
    float* zrp   = out;                               // Re(z): T*NCH floats
    float* r_f   = out + (size_t)T_STEPS * NCH;       // NCH floats
    float* phi_f = r_f + NCH;                         // NCH floats

    reshopf_kernel<<<NCH / 64, 64, 0, stream>>>(Xr, Xi, r0, phi0, om, zrp, r_f, phi_f);
}